// Round 1
// baseline (54.558 us; speedup 1.0000x reference)
//
#include <hip/hip_runtime.h>

// Problem constants (match reference)
#define PP 32   // patches
#define SS 4
#define CC 64
#define HH 128
#define WW 128
#define NC 32   // channels kept per patch
#define OO 32   // adaptive pool output size (MIN_SIZE)

// One thread per output element.
// Output layout: [P, S, NC, O, O] flattened -> idx = ((((p*S+s)*NC+c)*O)+o)*O + q
__global__ __launch_bounds__(256) void patch_sampler_kernel(
    const float* __restrict__ input,     // [P,S,C,H,W]
    const int*   __restrict__ size_raw,  // [P]
    const int*   __restrict__ pix,       // [P]
    const int*   __restrict__ channels,  // [P,NC]
    float*       __restrict__ out)       // [P,S,NC,O,O]
{
    const int idx = blockIdx.x * 256 + threadIdx.x;

    const int q = idx & (OO - 1);
    const int o = (idx >> 5) & (OO - 1);
    const int c = (idx >> 10) & (NC - 1);
    const int s = (idx >> 15) & (SS - 1);
    const int p = idx >> 17;

    // Per-patch crop parameters (wave-uniform within a block: p constant
    // across 131072 consecutive indices).
    const int size = size_raw[p] + OO;          // [32, 128]
    const int wr = WW - size + 1;
    const int hr = HH - size + 1;
    const int pm = pix[p] % (wr * hr);
    const int offy = pm / wr;
    const int offx = pm - offy * wr;
    const int ch = channels[p * NC + c];

    // torch adaptive_avg_pool bin bounds (O = 32 -> shifts)
    const int sy = offy + ((o * size) >> 5);
    const int ey = offy + (((o + 1) * size + 31) >> 5);
    const int sx = offx + ((q * size) >> 5);
    const int ex = offx + (((q + 1) * size + 31) >> 5);

    const float* base = input + ((size_t)((p * SS + s) * CC + ch)) * (HH * WW);

    float acc = 0.0f;
    for (int y = sy; y < ey; ++y) {
        const float* row = base + y * WW;
        for (int x = sx; x < ex; ++x) {
            acc += row[x];
        }
    }
    const float cnt = (float)((ey - sy) * (ex - sx));
    out[idx] = acc / cnt;
}

extern "C" void kernel_launch(void* const* d_in, const int* in_sizes, int n_in,
                              void* d_out, int out_size, void* d_ws, size_t ws_size,
                              hipStream_t stream) {
    const float* input    = (const float*)d_in[0];
    const int*   size_raw = (const int*)d_in[1];
    const int*   pix      = (const int*)d_in[2];
    const int*   channels = (const int*)d_in[3];
    float*       out      = (float*)d_out;

    const int total = PP * SS * NC * OO * OO;   // 4,194,304
    const int block = 256;
    const int grid = total / block;             // 16384
    patch_sampler_kernel<<<grid, block, 0, stream>>>(input, size_raw, pix, channels, out);
}